// Round 1
// baseline (84.897 us; speedup 1.0000x reference)
//
#include <hip/hip_runtime.h>
#include <hip/hip_bf16.h>
#include <stdint.h>

typedef __hip_bfloat16 bf16;
typedef __attribute__((ext_vector_type(8))) short short8;   // 8 bf16 (4 VGPRs) MFMA A/B frag
typedef __attribute__((ext_vector_type(4))) float f32x4;    // MFMA C/D frag

#define MFMA16(A,B,C) __builtin_amdgcn_mfma_f32_16x16x32_bf16(A,B,C,0,0,0)

// async global->LDS, 16B per lane. LDS dest = wave-uniform base + lane*16.
static __device__ __forceinline__ void g2lds16(const void* g, void* l) {
  __builtin_amdgcn_global_load_lds(
      (__attribute__((address_space(1))) void*)(g),
      (__attribute__((address_space(3))) void*)(l), 16, 0, 0);
}

// swizzled chunk index within a [rows][64 bf16] LDS tile (chunks = 8 bf16 = 16B)
// stored chunk = row*8 + (kc ^ (row&7)); involution -> same formula both sides.
static __device__ __forceinline__ int swz8(int row, int kc) {
  return row * 8 + (kc ^ (row & 7));
}

// ---------------- fp32 -> bf16 elementwise ----------------
__global__ void k_conv_bf16(const float* __restrict__ in, bf16* __restrict__ out, int n4) {
  int i = blockIdx.x * blockDim.x + threadIdx.x;
  if (i < n4) {
    float4 v = ((const float4*)in)[i];
    bf16* po = out + (size_t)i * 4;
    po[0] = __float2bfloat16(v.x);
    po[1] = __float2bfloat16(v.y);
    po[2] = __float2bfloat16(v.z);
    po[3] = __float2bfloat16(v.w);
  }
}

// ---------------- transpose + convert: in [R][Ncol] fp32 -> out [Ncol][R] bf16 ----------------
__global__ void k_convT(const float* __restrict__ in, bf16* __restrict__ out, int R, int Ncol) {
  int idx = blockIdx.x * blockDim.x + threadIdx.x;
  if (idx < R * Ncol) {
    int o = idx / R;
    int i = idx - o * R;
    out[idx] = __float2bfloat16(in[(size_t)i * Ncol + o]);
  }
}

// ---------------- bf16 GEMM: C[M][N] = A[M][K] * BT[N][K]^T ----------------
// 128x128 tile, BK=64, 4 waves (2x2), 64x64 per wave (4x4 frags of 16x16x32).
// EPI 0: qkv epilogue (relu+eps on cols<768), bf16 out. EPI 1: +bias, fp32 out.
template<int EPI>
__global__ __launch_bounds__(256, 2)
void k_gemm(const bf16* __restrict__ A, const bf16* __restrict__ BT,
            bf16* __restrict__ Cb, float* __restrict__ Cf,
            const float* __restrict__ bias, int M, int N, int K)
{
  __shared__ __align__(16) bf16 As[128 * 64];
  __shared__ __align__(16) bf16 Bs[128 * 64];
  const int tid = threadIdx.x;
  const int wave = tid >> 6, lane = tid & 63;
  const int lhi = lane >> 4, llo = lane & 15;
  const int wr = wave >> 1, wc = wave & 1;
  const int mBase = blockIdx.x * 128, nBase = blockIdx.y * 128;

  f32x4 acc[4][4] = {};

  for (int kt = 0; kt < K; kt += 64) {
    __syncthreads();
    // stage A and B tiles: 128x64 bf16 = 1024 chunks of 16B each
    for (int i = 0; i < 4; ++i) {
      int c = (wave * 4 + i) * 64 + lane;      // chunk 0..1023
      int row = c >> 3;
      int kc = (c & 7) ^ (row & 7);            // pre-swizzled global source chunk
      g2lds16(A  + (size_t)(mBase + row) * K + kt + kc * 8, As + (c & ~63) * 8);
      g2lds16(BT + (size_t)(nBase + row) * K + kt + kc * 8, Bs + (c & ~63) * 8);
    }
    __syncthreads();
    for (int kk = 0; kk < 2; ++kk) {
      const int kc = kk * 4 + lhi;
      short8 a[4], b[4];
      for (int mi = 0; mi < 4; ++mi) {
        int row = wr * 64 + mi * 16 + llo;
        a[mi] = *(const short8*)(As + swz8(row, kc) * 8);
      }
      for (int ni = 0; ni < 4; ++ni) {
        int row = wc * 64 + ni * 16 + llo;
        b[ni] = *(const short8*)(Bs + swz8(row, kc) * 8);
      }
      for (int mi = 0; mi < 4; ++mi)
        for (int ni = 0; ni < 4; ++ni)
          acc[mi][ni] = MFMA16(a[mi], b[ni], acc[mi][ni]);
    }
  }

  for (int mi = 0; mi < 4; ++mi)
    for (int ni = 0; ni < 4; ++ni)
      for (int j = 0; j < 4; ++j) {
        int row = mBase + wr * 64 + mi * 16 + lhi * 4 + j;
        int col = nBase + wc * 64 + ni * 16 + llo;
        float v = acc[mi][ni][j];
        if (EPI == 0) {
          if (col < 768) v = fmaxf(v, 0.f) + 1e-6f;   // relu+eps on q,k only
          Cb[(size_t)row * N + col] = __float2bfloat16(v);
        } else {
          Cf[(size_t)row * N + col] = v + bias[col];
        }
      }
}

// ---------------- V transpose: qkv v-section [b,n][h*64+d] -> vT[bh][d][n] ----------------
__global__ void k_transpose_v(const bf16* __restrict__ qkv, bf16* __restrict__ vT) {
  __shared__ bf16 t[64][66];
  int bh = blockIdx.x, b = bh / 6, h = bh - b * 6;
  int n0 = blockIdx.y * 64;
  int r = threadIdx.x >> 2;                 // 0..63
  int cg = (threadIdx.x & 3) * 16;          // 0,16,32,48
  const bf16* src = qkv + ((size_t)b * 1024 + n0 + r) * 1152 + 768 + h * 64 + cg;
  short8 v0 = *(const short8*)src;
  short8 v1 = *(const short8*)(src + 8);
  for (int j = 0; j < 8; ++j) {
    t[r][cg + j]     = ((const bf16*)&v0)[j];
    t[r][cg + 8 + j] = ((const bf16*)&v1)[j];
  }
  __syncthreads();
  bf16* dst = vT + ((size_t)bh * 64 + r) * 1024 + n0 + cg;
  for (int j = 0; j < 16; ++j) dst[j] = t[cg + j][r];
}

// ---------------- fused masked linear attention ----------------
// block = (bh, q-tile of 128). 4 waves; wave owns 32 q-rows.
// out[q][d] = sum_m (q.k * mask) v / (rowsum + eps)
__global__ __launch_bounds__(256, 2)
void k_attn(const bf16* __restrict__ qkv,   // [8192][1152]
            const bf16* __restrict__ vT,    // [48][64][1024]
            const float* __restrict__ mask, // [1024][1024] fp32
            bf16* __restrict__ out)         // [8192][384]
{
  __shared__ __align__(16) bf16 Qs[128 * 64];
  __shared__ __align__(16) bf16 Ks[64 * 64];
  __shared__ __align__(16) bf16 Vs[64 * 64];
  __shared__ __align__(16) bf16 Ps[4][32 * 64];
  const int bh = blockIdx.x, qt = blockIdx.y;
  const int b = bh / 6, h = bh - b * 6;
  const int tid = threadIdx.x, wave = tid >> 6, lane = tid & 63;
  const int lhi = lane >> 4, llo = lane & 15;
  const size_t row0 = (size_t)b * 1024;

  // stage Q tile once: 128 rows x 64 d
  for (int i = 0; i < 4; ++i) {
    int c = (wave * 4 + i) * 64 + lane;
    int row = c >> 3;
    int kc = (c & 7) ^ (row & 7);
    g2lds16(qkv + (row0 + qt * 128 + row) * 1152 + h * 64 + kc * 8, Qs + (c & ~63) * 8);
  }

  f32x4 accO[2][4] = {};
  float zacc[2][4] = {};

  for (int mt = 0; mt < 16; ++mt) {
    const int mBase = mt * 64;
    __syncthreads();
    for (int i = 0; i < 2; ++i) {
      int c = (wave * 2 + i) * 64 + lane;    // 0..511
      int row = c >> 3;
      int kc = (c & 7) ^ (row & 7);
      g2lds16(qkv + (row0 + mBase + row) * 1152 + 384 + h * 64 + kc * 8, Ks + (c & ~63) * 8);
      g2lds16(vT + ((size_t)bh * 64 + row) * 1024 + mBase + kc * 8,      Vs + (c & ~63) * 8);
    }
    __syncthreads();

    // S = Q K^T (per-wave 32x64)
    f32x4 s[2][4] = {};
    for (int kk = 0; kk < 2; ++kk) {
      const int kc = kk * 4 + lhi;
      short8 aq[2], bk[4];
      for (int st = 0; st < 2; ++st) {
        int row = wave * 32 + st * 16 + llo;
        aq[st] = *(const short8*)(Qs + swz8(row, kc) * 8);
      }
      for (int mi = 0; mi < 4; ++mi) {
        int row = mi * 16 + llo;
        bk[mi] = *(const short8*)(Ks + swz8(row, kc) * 8);
      }
      for (int st = 0; st < 2; ++st)
        for (int mi = 0; mi < 4; ++mi)
          s[st][mi] = MFMA16(aq[st], bk[mi], s[st][mi]);
    }

    // P = S*mask; z rowsum; write P (bf16, swizzled) to per-wave LDS
    bf16* Pw = (bf16*)Ps + wave * 2048;
    for (int st = 0; st < 2; ++st)
      for (int j = 0; j < 4; ++j) {
        int qq = st * 16 + lhi * 4 + j;            // 0..31 in wave tile
        int qg = qt * 128 + wave * 32 + qq;        // global n
        const float* mrow = mask + (size_t)qg * 1024 + mBase;
        float zp = 0.f;
        for (int mi = 0; mi < 4; ++mi) {
          int m = mi * 16 + llo;
          float p = s[st][mi][j] * mrow[m];
          zp += p;
          Pw[swz8(qq, m >> 3) * 8 + (m & 7)] = __float2bfloat16(p);
        }
        zacc[st][j] += zp;
      }

    // accO += P @ V   (A = P [32 x 64m], B^T = Vs [d][m])
    for (int kk = 0; kk < 2; ++kk) {
      const int kc = kk * 4 + lhi;
      short8 ap[2], bv[4];
      for (int st = 0; st < 2; ++st) {
        int row = st * 16 + llo;
        ap[st] = *(const short8*)(Pw + swz8(row, kc) * 8);
      }
      for (int ni = 0; ni < 4; ++ni) {
        int row = ni * 16 + llo;
        bv[ni] = *(const short8*)(Vs + swz8(row, kc) * 8);
      }
      for (int st = 0; st < 2; ++st)
        for (int ni = 0; ni < 4; ++ni)
          accO[st][ni] = MFMA16(ap[st], bv[ni], accO[st][ni]);
    }
  }

  // z reduce across the 16 col-lanes, scale, store
  for (int st = 0; st < 2; ++st)
    for (int j = 0; j < 4; ++j) {
      float z = zacc[st][j];
      z += __shfl_xor(z, 1);
      z += __shfl_xor(z, 2);
      z += __shfl_xor(z, 4);
      z += __shfl_xor(z, 8);
      float zi = 1.f / (z + 1e-6f);
      int n = qt * 128 + wave * 32 + st * 16 + lhi * 4 + j;
      size_t orow = ((size_t)b * 1024 + n) * 384 + h * 64;
      for (int ni = 0; ni < 4; ++ni)
        out[orow + ni * 16 + llo] = __float2bfloat16(accO[st][ni][j] * zi);
    }
}

extern "C" void kernel_launch(void* const* d_in, const int* in_sizes, int n_in,
                              void* d_out, int out_size, void* d_ws, size_t ws_size,
                              hipStream_t stream) {
  (void)in_sizes; (void)n_in; (void)out_size; (void)ws_size;
  const float* x    = (const float*)d_in[0];   // [8,1024,384]
  const float* wqkv = (const float*)d_in[1];   // [384,1152]
  const float* wout = (const float*)d_in[2];   // [384,384]
  const float* bout = (const float*)d_in[3];   // [384]
  const float* mask = (const float*)d_in[4];   // [1024,1024]
  float* outp = (float*)d_out;

  char* ws = (char*)d_ws;
  bf16* xb    = (bf16*)(ws);                        // 8192*384       (6,291,456 B)
  bf16* wqkvT = (bf16*)(ws + 6291456);              // 1152*384       (884,736 B)
  bf16* woutT = (bf16*)(ws + 7176192);              // 384*384        (294,912 B)
  bf16* qkvb  = (bf16*)(ws + 7471104);              // 8192*1152      (18,874,368 B)
  bf16* vTb   = (bf16*)(ws + 26345472);             // 48*64*1024     (6,291,456 B)
  bf16* ab    = (bf16*)(ws + 32636928);             // 8192*384       (6,291,456 B)

  k_conv_bf16<<<dim3(3072), dim3(256), 0, stream>>>(x, xb, 786432);
  k_convT<<<dim3((442368 + 255) / 256), dim3(256), 0, stream>>>(wqkv, wqkvT, 384, 1152);
  k_convT<<<dim3((147456 + 255) / 256), dim3(256), 0, stream>>>(wout, woutT, 384, 384);

  k_gemm<0><<<dim3(64, 9), dim3(256), 0, stream>>>(xb, wqkvT, qkvb, nullptr, nullptr,
                                                   8192, 1152, 384);
  k_transpose_v<<<dim3(48, 16), dim3(256), 0, stream>>>(qkvb, vTb);
  k_attn<<<dim3(48, 8), dim3(256), 0, stream>>>(qkvb, vTb, mask, ab);
  k_gemm<1><<<dim3(64, 3), dim3(256), 0, stream>>>(ab, woutT, nullptr, outp, bout,
                                                   8192, 384, 384);
}

// Round 2
// 71.653 us; speedup vs baseline: 1.1848x; 1.1848x over previous
//
#include <hip/hip_runtime.h>
#include <hip/hip_bf16.h>
#include <stdint.h>

typedef __hip_bfloat16 bf16;
typedef __attribute__((ext_vector_type(8))) short short8;   // 8 bf16 (4 VGPRs) MFMA A/B frag
typedef __attribute__((ext_vector_type(4))) float f32x4;    // MFMA C/D frag

#define MFMA16(A,B,C) __builtin_amdgcn_mfma_f32_16x16x32_bf16(A,B,C,0,0,0)

// async global->LDS, 16B per lane. LDS dest = wave-uniform base + lane*16.
static __device__ __forceinline__ void g2lds16(const void* g, void* l) {
  __builtin_amdgcn_global_load_lds(
      (__attribute__((address_space(1))) void*)(g),
      (__attribute__((address_space(3))) void*)(l), 16, 0, 0);
}

// swizzled chunk index within a [rows][64 bf16] LDS tile (chunks = 8 bf16 = 16B)
// stored chunk = row*8 + (kc ^ (row&7)); involution -> same formula both sides.
static __device__ __forceinline__ int swz8(int row, int kc) {
  return row * 8 + (kc ^ (row & 7));
}

// ---------------- fp32 -> bf16 elementwise ----------------
__global__ void k_conv_bf16(const float* __restrict__ in, bf16* __restrict__ out, int n4) {
  int i = blockIdx.x * blockDim.x + threadIdx.x;
  if (i < n4) {
    float4 v = ((const float4*)in)[i];
    bf16* po = out + (size_t)i * 4;
    po[0] = __float2bfloat16(v.x);
    po[1] = __float2bfloat16(v.y);
    po[2] = __float2bfloat16(v.z);
    po[3] = __float2bfloat16(v.w);
  }
}

// ---------------- transpose + convert: in [R][Ncol] fp32 -> out [Ncol][R] bf16 ----------------
__global__ void k_convT(const float* __restrict__ in, bf16* __restrict__ out, int R, int Ncol) {
  int idx = blockIdx.x * blockDim.x + threadIdx.x;
  if (idx < R * Ncol) {
    int o = idx / R;
    int i = idx - o * R;
    out[idx] = __float2bfloat16(in[(size_t)i * Ncol + o]);
  }
}

// ---------------- bf16 GEMM: C[M][N] = A[M][K] * BT[N][K]^T ----------------
// 128x128 tile, BK=64, 4 waves (2x2), 64x64 per wave (4x4 frags of 16x16x32).
// EPI 0: qkv epilogue (relu+eps on cols<768), bf16 out. EPI 1: +bias, fp32 out.
template<int EPI>
__global__ __launch_bounds__(256, 2)
void k_gemm(const bf16* __restrict__ A, const bf16* __restrict__ BT,
            bf16* __restrict__ Cb, float* __restrict__ Cf,
            const float* __restrict__ bias, int M, int N, int K)
{
  __shared__ __align__(16) bf16 As[128 * 64];
  __shared__ __align__(16) bf16 Bs[128 * 64];
  const int tid = threadIdx.x;
  const int wave = tid >> 6, lane = tid & 63;
  const int lhi = lane >> 4, llo = lane & 15;
  const int wr = wave >> 1, wc = wave & 1;
  const int mBase = blockIdx.x * 128, nBase = blockIdx.y * 128;

  f32x4 acc[4][4] = {};

  for (int kt = 0; kt < K; kt += 64) {
    __syncthreads();
    // stage A and B tiles: 128x64 bf16 = 1024 chunks of 16B each
    for (int i = 0; i < 4; ++i) {
      int c = (wave * 4 + i) * 64 + lane;      // chunk 0..1023
      int row = c >> 3;
      int kc = (c & 7) ^ (row & 7);            // pre-swizzled global source chunk
      g2lds16(A  + (size_t)(mBase + row) * K + kt + kc * 8, As + (c & ~63) * 8);
      g2lds16(BT + (size_t)(nBase + row) * K + kt + kc * 8, Bs + (c & ~63) * 8);
    }
    __syncthreads();
    for (int kk = 0; kk < 2; ++kk) {
      const int kc = kk * 4 + lhi;
      short8 a[4], b[4];
      for (int mi = 0; mi < 4; ++mi) {
        int row = wr * 64 + mi * 16 + llo;
        a[mi] = *(const short8*)(As + swz8(row, kc) * 8);
      }
      for (int ni = 0; ni < 4; ++ni) {
        int row = wc * 64 + ni * 16 + llo;
        b[ni] = *(const short8*)(Bs + swz8(row, kc) * 8);
      }
      for (int mi = 0; mi < 4; ++mi)
        for (int ni = 0; ni < 4; ++ni)
          acc[mi][ni] = MFMA16(a[mi], b[ni], acc[mi][ni]);
    }
  }

  for (int mi = 0; mi < 4; ++mi)
    for (int ni = 0; ni < 4; ++ni)
      for (int j = 0; j < 4; ++j) {
        int row = mBase + wr * 64 + mi * 16 + lhi * 4 + j;
        int col = nBase + wc * 64 + ni * 16 + llo;
        float v = acc[mi][ni][j];
        if (EPI == 0) {
          if (col < 768) v = fmaxf(v, 0.f) + 1e-6f;   // relu+eps on q,k only
          Cb[(size_t)row * N + col] = __float2bfloat16(v);
        } else {
          Cf[(size_t)row * N + col] = v + bias[col];
        }
      }
}

// ---------------- V transpose: qkv v-section [b,n][h*64+d] -> vT[bh][d][n] ----------------
__global__ void k_transpose_v(const bf16* __restrict__ qkv, bf16* __restrict__ vT) {
  __shared__ bf16 t[64][66];
  int bh = blockIdx.x, b = bh / 6, h = bh - b * 6;
  int n0 = blockIdx.y * 64;
  int r = threadIdx.x >> 2;                 // 0..63
  int cg = (threadIdx.x & 3) * 16;          // 0,16,32,48
  const bf16* src = qkv + ((size_t)b * 1024 + n0 + r) * 1152 + 768 + h * 64 + cg;
  short8 v0 = *(const short8*)src;
  short8 v1 = *(const short8*)(src + 8);
  for (int j = 0; j < 8; ++j) {
    t[r][cg + j]     = ((const bf16*)&v0)[j];
    t[r][cg + 8 + j] = ((const bf16*)&v1)[j];
  }
  __syncthreads();
  bf16* dst = vT + ((size_t)bh * 64 + r) * 1024 + n0 + cg;
  for (int j = 0; j < 16; ++j) dst[j] = t[cg + j][r];
}

// ---------------- fused masked linear attention ----------------
// block = (bh, q-tile of 64). 4 waves; wave owns 16 q-rows.
// K/V double-buffered in LDS; Q frags hoisted to registers; mask preloaded
// into registers at iteration top so L2 latency hides under QK^T.
__global__ __launch_bounds__(256, 3)
void k_attn(const bf16* __restrict__ qkv,   // [8192][1152]
            const bf16* __restrict__ vT,    // [48][64][1024]
            const float* __restrict__ mask, // [1024][1024] fp32
            bf16* __restrict__ out)         // [8192][384]
{
  __shared__ __align__(16) bf16 Qs[64 * 64];
  __shared__ __align__(16) bf16 Ks[2][64 * 64];
  __shared__ __align__(16) bf16 Vs[2][64 * 64];
  __shared__ __align__(16) bf16 Ps[4][16 * 64];
  const int bh = blockIdx.x, qt = blockIdx.y;
  const int b = bh / 6, h = bh - b * 6;
  const int tid = threadIdx.x, wave = tid >> 6, lane = tid & 63;
  const int lhi = lane >> 4, llo = lane & 15;
  const size_t row0 = (size_t)b * 1024;

  // stage Q tile (64 rows x 64 d): 512 chunks of 16B
  for (int i = 0; i < 2; ++i) {
    int c = (wave * 2 + i) * 64 + lane;
    int row = c >> 3;
    int kc = (c & 7) ^ (row & 7);
    g2lds16(qkv + (row0 + qt * 64 + row) * 1152 + h * 64 + kc * 8, Qs + (c & ~63) * 8);
  }

  // stage K/V tile mt into buffer buf
  auto stageKV = [&](int mt, int buf) {
    for (int i = 0; i < 2; ++i) {
      int c = (wave * 2 + i) * 64 + lane;
      int row = c >> 3;
      int kc = (c & 7) ^ (row & 7);
      g2lds16(qkv + (row0 + mt * 64 + row) * 1152 + 384 + h * 64 + kc * 8,
              Ks[buf] + (c & ~63) * 8);
      g2lds16(vT + ((size_t)bh * 64 + row) * 1024 + mt * 64 + kc * 8,
              Vs[buf] + (c & ~63) * 8);
    }
  };
  stageKV(0, 0);
  __syncthreads();   // Q + KV0 resident

  // hoist Q fragments (row = wave*16+llo)
  short8 aq[2];
  for (int kk = 0; kk < 2; ++kk)
    aq[kk] = *(const short8*)(Qs + swz8(wave * 16 + llo, kk * 4 + lhi) * 8);

  f32x4 accO[4] = {};   // [ni] over d
  float zacc[4] = {};   // [j]  row partials (per-lane, over m==llo mod 16)

  const float* mbase = mask + (size_t)(qt * 64 + wave * 16 + lhi * 4) * 1024;

  for (int mt = 0; mt < 16; ++mt) {
    const int cur = mt & 1;
    // prefetch next K/V while computing this tile
    if (mt < 15) stageKV(mt + 1, cur ^ 1);

    // preload mask values (independent of S -> latency hidden under QK^T)
    float mreg[4][4];
    for (int j = 0; j < 4; ++j)
      for (int mi = 0; mi < 4; ++mi)
        mreg[j][mi] = mbase[(size_t)j * 1024 + mt * 64 + mi * 16 + llo];

    // S = Q K^T (wave: 16 q-rows x 64 m)
    f32x4 s[4] = {};
    for (int kk = 0; kk < 2; ++kk) {
      const int kc = kk * 4 + lhi;
      short8 bk[4];
      for (int mi = 0; mi < 4; ++mi)
        bk[mi] = *(const short8*)(Ks[cur] + swz8(mi * 16 + llo, kc) * 8);
      for (int mi = 0; mi < 4; ++mi)
        s[mi] = MFMA16(aq[kk], bk[mi], s[mi]);
    }

    // P = S*mask; accumulate z; write P (bf16, swizzled) to per-wave LDS
    bf16* Pw = (bf16*)Ps[wave];
    for (int j = 0; j < 4; ++j) {
      const int qq = lhi * 4 + j;
      float zp = 0.f;
      for (int mi = 0; mi < 4; ++mi) {
        int m = mi * 16 + llo;
        float p = s[mi][j] * mreg[j][mi];
        zp += p;
        Pw[swz8(qq, m >> 3) * 8 + (m & 7)] = __float2bfloat16(p);
      }
      zacc[j] += zp;
    }

    // accO += P @ V  (A = P [16 x 64m], B = Vs [d][m])
    for (int kk = 0; kk < 2; ++kk) {
      const int kc = kk * 4 + lhi;
      short8 ap = *(const short8*)(Pw + swz8(llo, kc) * 8);
      short8 bv[4];
      for (int ni = 0; ni < 4; ++ni)
        bv[ni] = *(const short8*)(Vs[cur] + swz8(ni * 16 + llo, kc) * 8);
      for (int ni = 0; ni < 4; ++ni)
        accO[ni] = MFMA16(ap, bv[ni], accO[ni]);
    }
    __syncthreads();  // next-tile staging complete; all waves done with buf[cur]
  }

  // z reduce across the 16 col-lanes, scale, store
  for (int j = 0; j < 4; ++j) {
    float z = zacc[j];
    z += __shfl_xor(z, 1);
    z += __shfl_xor(z, 2);
    z += __shfl_xor(z, 4);
    z += __shfl_xor(z, 8);
    float zi = 1.f / (z + 1e-6f);
    int n = qt * 64 + wave * 16 + lhi * 4 + j;
    size_t orow = ((size_t)b * 1024 + n) * 384 + h * 64;
    for (int ni = 0; ni < 4; ++ni)
      out[orow + ni * 16 + llo] = __float2bfloat16(accO[ni][j] * zi);
  }
}

extern "C" void kernel_launch(void* const* d_in, const int* in_sizes, int n_in,
                              void* d_out, int out_size, void* d_ws, size_t ws_size,
                              hipStream_t stream) {
  (void)in_sizes; (void)n_in; (void)out_size; (void)ws_size;
  const float* x    = (const float*)d_in[0];   // [8,1024,384]
  const float* wqkv = (const float*)d_in[1];   // [384,1152]
  const float* wout = (const float*)d_in[2];   // [384,384]
  const float* bout = (const float*)d_in[3];   // [384]
  const float* mask = (const float*)d_in[4];   // [1024,1024]
  float* outp = (float*)d_out;

  char* ws = (char*)d_ws;
  bf16* xb    = (bf16*)(ws);                        // 8192*384       (6,291,456 B)
  bf16* wqkvT = (bf16*)(ws + 6291456);              // 1152*384       (884,736 B)
  bf16* woutT = (bf16*)(ws + 7176192);              // 384*384        (294,912 B)
  bf16* qkvb  = (bf16*)(ws + 7471104);              // 8192*1152      (18,874,368 B)
  bf16* vTb   = (bf16*)(ws + 26345472);             // 48*64*1024     (6,291,456 B)
  bf16* ab    = (bf16*)(ws + 32636928);             // 8192*384       (6,291,456 B)

  k_conv_bf16<<<dim3(3072), dim3(256), 0, stream>>>(x, xb, 786432);
  k_convT<<<dim3((442368 + 255) / 256), dim3(256), 0, stream>>>(wqkv, wqkvT, 384, 1152);
  k_convT<<<dim3((147456 + 255) / 256), dim3(256), 0, stream>>>(wout, woutT, 384, 384);

  k_gemm<0><<<dim3(64, 9), dim3(256), 0, stream>>>(xb, wqkvT, qkvb, nullptr, nullptr,
                                                   8192, 1152, 384);
  k_transpose_v<<<dim3(48, 16), dim3(256), 0, stream>>>(qkvb, vTb);
  k_attn<<<dim3(48, 16), dim3(256), 0, stream>>>(qkvb, vTb, mask, ab);
  k_gemm<1><<<dim3(64, 3), dim3(256), 0, stream>>>(ab, woutT, nullptr, outp, bout,
                                                   8192, 384, 384);
}